// Round 1
// baseline (199.270 us; speedup 1.0000x reference)
//
#include <hip/hip_runtime.h>

// RFCM loss, fully fused single-pass + tiny finalize.
// B=2, K=4, D=H=W=128. Output: scalar float.
//
// Algebra:
//  mean(J1) = (1/(B*N)) * sum_{b,k} [ A_bk - Sim_bk^2 / Sm_bk ]
//    with Sm=sum mem, Sim=sum mem*img, A=sum mem*img^2, mem=y_pred^2
//  mean(J2) = (1/(B*N)) * sum_n [ Sm_v*Sbk_v - Sm_v^2 - sum_k m*bk + sum_k m^2 ]
//    with bk = box27(mem_k) (27-sum incl center, zero pad), per-voxel sums over k.

#define BB 2
#define KK 4
#define DD 128
#define HH 128
#define WW 128
#define HT 4            // h rows computed per block
#define SD 16           // d planes per block
#define NBH (HH / HT)   // 32
#define NBD (DD / SD)   // 8
#define ROWS 6          // HT + 2 halo
#define COLS 130        // WW + 2 zero-pad columns
#define NT 256

__global__ __launch_bounds__(NT) void rfcm_main(
    const float* __restrict__ yp, const float* __restrict__ img,
    double* __restrict__ ws)
{
    // ring of 3 d-planes per cluster k: raw[k][slot][row][col], squared values
    __shared__ __align__(16) float raw[KK * 3 * ROWS * COLS];

    const int tid = threadIdx.x;
    const int w  = tid & 127;   // 0..127 (column)
    const int hy = tid >> 7;    // 0..1

    int bid = blockIdx.x;
    const int ht  = bid % NBH; bid /= NBH;
    const int dsb = bid % NBD; bid /= NBD;
    const int b   = bid;                 // 0..1
    const int h0  = ht * HT;
    const int d0  = dsb * SD;

    // zero the pad columns once (never overwritten afterwards)
    for (int i = tid; i < KK * 3 * ROWS; i += NT) {
        raw[i * COLS] = 0.f;
        raw[i * COLS + (COLS - 1)] = 0.f;
    }

    auto load_plane = [&](int slot, int d) {
        const bool dok = ((unsigned)d < (unsigned)DD);
        #pragma unroll
        for (int k = 0; k < KK; k++) {
            #pragma unroll
            for (int i = 0; i < 3; i++) {
                const int r = 3 * hy + i;      // rows 0..5 covered by the two hy groups
                const int h = h0 - 1 + r;
                float val = 0.f;
                if (dok && ((unsigned)h < (unsigned)HH)) {
                    const float t = yp[(((size_t)(b * KK + k) * DD + d) * HH + h) * WW + w];
                    val = t * t;
                }
                raw[((k * 3 + slot) * ROWS + r) * COLS + (w + 1)] = val;
            }
        }
    };

    float s9p[KK][2], s9c[KK][2], s9n[KK][2];

    auto calc_s9 = [&](int slot, float (&s9)[KK][2]) {
        #pragma unroll
        for (int k = 0; k < KK; k++) {
            float rs[4];
            #pragma unroll
            for (int t = 0; t < 4; t++) {
                const float* p = &raw[((k * 3 + slot) * ROWS + (2 * hy + t)) * COLS + w];
                rs[t] = p[0] + p[1] + p[2];   // cols w-1..w+1 of center w (pad-shifted)
            }
            s9[k][0] = rs[0] + rs[1] + rs[2]; // voxel row j = 2*hy
            s9[k][1] = rs[1] + rs[2] + rs[3]; // voxel row j = 2*hy+1
        }
    };

    load_plane(0, d0 - 1);
    load_plane(1, d0);
    __syncthreads();
    calc_s9(0, s9p);
    calc_s9(1, s9c);

    double sm[KK] = {0, 0, 0, 0};
    double si[KK] = {0, 0, 0, 0};
    double sa[KK] = {0, 0, 0, 0};
    double j2 = 0;

    for (int i = 0; i < SD; i++) {
        const int d  = d0 + i;
        const int sn = (2 + i) % 3;   // slot for plane d+1
        const int sc = (1 + i) % 3;   // slot holding plane d

        load_plane(sn, d + 1);
        __syncthreads();
        calc_s9(sn, s9n);

        #pragma unroll
        for (int v = 0; v < 2; v++) {
            const int j = 2 * hy + v;             // owned row in tile (0..3)
            const float iv = img[(((size_t)b * DD + d) * HH + (h0 + j)) * WW + w];
            float summ = 0.f, sumbk = 0.f, cross = 0.f;
            #pragma unroll
            for (int k = 0; k < KK; k++) {
                const float m  = raw[((k * 3 + sc) * ROWS + (j + 1)) * COLS + (w + 1)];
                const float bk = s9p[k][v] + s9c[k][v] + s9n[k][v];
                summ  += m;
                sumbk += bk;
                cross += m * bk - m * m;
                sm[k] += (double)m;
                si[k] += (double)(m * iv);
                sa[k] += (double)(m * iv * iv);
            }
            j2 += (double)(summ * sumbk - summ * summ - cross);
        }

        #pragma unroll
        for (int k = 0; k < KK; k++) {
            s9p[k][0] = s9c[k][0]; s9p[k][1] = s9c[k][1];
            s9c[k][0] = s9n[k][0]; s9c[k][1] = s9n[k][1];
        }
    }

    // ---- block reduction of 13 scalars ----
    double q[13];
    #pragma unroll
    for (int k = 0; k < KK; k++) { q[k] = sm[k]; q[4 + k] = si[k]; q[8 + k] = sa[k]; }
    q[12] = j2;

    #pragma unroll
    for (int qq = 0; qq < 13; qq++) {
        double v = q[qq];
        #pragma unroll
        for (int off = 32; off > 0; off >>= 1) v += __shfl_down(v, off, 64);
        q[qq] = v;
    }

    __syncthreads();                 // done with raw; reuse as reduction scratch
    double* red = (double*)raw;
    const int lane = tid & 63, wid = tid >> 6;
    if (lane == 0) {
        #pragma unroll
        for (int qq = 0; qq < 13; qq++) red[wid * 13 + qq] = q[qq];
    }
    __syncthreads();
    if (tid < 13) {
        const double s = red[tid] + red[13 + tid] + red[26 + tid] + red[39 + tid];
        int idx;
        if      (tid < 4)  idx = b * KK + tid;              // Sm  -> ws[0..7]
        else if (tid < 8)  idx = 8  + b * KK + (tid - 4);   // Sim -> ws[8..15]
        else if (tid < 12) idx = 16 + b * KK + (tid - 8);   // A   -> ws[16..23]
        else               idx = 24;                        // J2  -> ws[24]
        unsafeAtomicAdd(&ws[idx], s);
    }
}

__global__ void rfcm_fin(const double* __restrict__ ws, float* __restrict__ out)
{
    if (threadIdx.x == 0 && blockIdx.x == 0) {
        double j1 = 0;
        #pragma unroll
        for (int i = 0; i < BB * KK; i++)
            j1 += ws[16 + i] - ws[8 + i] * ws[8 + i] / ws[i];
        const double invBN = 1.0 / ((double)BB * (double)DD * (double)HH * (double)WW);
        out[0] = (float)(j1 * invBN + 0.0008 * ws[24] * invBN);
    }
}

extern "C" void kernel_launch(void* const* d_in, const int* in_sizes, int n_in,
                              void* d_out, int out_size, void* d_ws, size_t ws_size,
                              hipStream_t stream) {
    const float* yp  = (const float*)d_in[0];   // y_pred [2,4,128,128,128]
    const float* img = (const float*)d_in[1];   // image  [2,1,128,128,128]
    float* out = (float*)d_out;
    double* ws = (double*)d_ws;

    hipMemsetAsync(d_ws, 0, 25 * sizeof(double), stream);

    dim3 grid(BB * NBD * NBH);   // 512 blocks
    rfcm_main<<<grid, NT, 0, stream>>>(yp, img, ws);
    rfcm_fin<<<1, 64, 0, stream>>>(ws, out);
}

// Round 2
// 170.860 us; speedup vs baseline: 1.1663x; 1.1663x over previous
//
#include <hip/hip_runtime.h>

// RFCM loss, fused single pass + finalize.
// B=2, K=4, D=H=W=128. Output scalar.
//
// mean(J1) = (1/(B*N)) * sum_{b,k} [ A_bk - Sim_bk^2 / Sm_bk ]
//   Sm=sum mem, Sim=sum mem*img, A=sum mem*img^2, mem=y_pred^2
// mean(J2) = (1/(B*N)) * sum_n [ Sm_v*Sbk_v - Sm_v^2 - sum_k m*bk + sum_k m^2 ]
//   bk = box27(mem_k) incl center, zero pad.
//
// R2: latency-bound fix — grid 512->2048 (SD 16->4, 4 blocks/CU resident),
// register-prefetch software pipeline (ds_write of prefetched plane one full
// iteration after issue), float4 staging loads, f32 thread accumulation.

#define BB 2
#define KK 4
#define DD 128
#define HH 128
#define WW 128
#define HT 4            // h rows per block
#define SD 4            // d planes per block
#define NBH (HH / HT)   // 32
#define NBD (DD / SD)   // 32
#define ROWS 6          // HT + 2 halo
#define COLS 130        // WW + 2 zero pad
#define NT 256

__global__ __launch_bounds__(NT) void rfcm_main(
    const float* __restrict__ yp, const float* __restrict__ img,
    double* __restrict__ ws)
{
    // ring of 3 d-planes per cluster: squared memberships
    __shared__ __align__(16) float raw[KK * 3 * ROWS * COLS];  // 37.4 KB

    const int tid = threadIdx.x;
    const int w  = tid & 127;
    const int hy = tid >> 7;    // 0..1 ; owns tile rows 2hy, 2hy+1

    int bid = blockIdx.x;
    const int ht  = bid % NBH; bid /= NBH;
    const int dsb = bid % NBD; bid /= NBD;
    const int b   = bid;
    const int h0  = ht * HT;
    const int d0  = dsb * SD;

    // zero pad columns (written once)
    for (int i = tid; i < KK * 3 * ROWS; i += NT) {
        raw[i * COLS] = 0.f;
        raw[i * COLS + (COLS - 1)] = 0.f;
    }

    // ---- staging: 24 rows (K*6) x 128 cols = 768 float4, 3 per thread ----
    auto loadP = [&](int d, float4 (&P)[3]) {
        const bool dok = ((unsigned)d < (unsigned)DD);
        #pragma unroll
        for (int c = 0; c < 3; c++) {
            const int f   = c * NT + tid;
            const int row = f >> 5;            // 0..23
            const int w4  = (f & 31) << 2;
            const int k   = row / 6;
            const int r   = row - 6 * k;
            const int h   = h0 - 1 + r;
            float4 v = make_float4(0.f, 0.f, 0.f, 0.f);
            if (dok && ((unsigned)h < (unsigned)HH)) {
                v = *(const float4*)(yp +
                    ((((size_t)(b * KK + k) * DD + d) * HH + h) << 7) + w4);
            }
            v.x *= v.x; v.y *= v.y; v.z *= v.z; v.w *= v.w;
            P[c] = v;
        }
    };
    auto storeP = [&](const float4 (&P)[3], int slot) {
        #pragma unroll
        for (int c = 0; c < 3; c++) {
            const int f   = c * NT + tid;
            const int row = f >> 5;
            const int w4  = (f & 31) << 2;
            const int k   = row / 6;
            const int r   = row - 6 * k;
            float* q = &raw[((k * 3 + slot) * ROWS + r) * COLS + w4 + 1];
            q[0] = P[c].x; q[1] = P[c].y; q[2] = P[c].z; q[3] = P[c].w;
        }
    };

    float s9p[KK][2], s9c[KK][2], s9n[KK][2];
    auto calc_s9 = [&](int slot, float (&s9)[KK][2]) {
        #pragma unroll
        for (int k = 0; k < KK; k++) {
            float rs[4];
            #pragma unroll
            for (int t = 0; t < 4; t++) {
                const float* p = &raw[((k * 3 + slot) * ROWS + (2 * hy + t)) * COLS + w];
                rs[t] = p[0] + p[1] + p[2];
            }
            s9[k][0] = rs[0] + rs[1] + rs[2];
            s9[k][1] = rs[1] + rs[2] + rs[3];
        }
    };

    float4 P[3];
    // prologue: planes d0-1, d0 into LDS; prefetch d0+1 into regs
    loadP(d0 - 1, P); storeP(P, 0);
    loadP(d0,     P); storeP(P, 1);
    loadP(d0 + 1, P);
    __syncthreads();
    calc_s9(0, s9p);
    calc_s9(1, s9c);

    float smf[KK] = {0,0,0,0}, sif[KK] = {0,0,0,0}, saf[KK] = {0,0,0,0};
    float j2f = 0.f;

    #pragma unroll
    for (int i = 0; i < SD; i++) {
        const int d  = d0 + i;
        const int sn = (2 + i) % 3;   // slot receiving plane d+1
        const int sc = (1 + i) % 3;   // slot holding plane d

        storeP(P, sn);                // waits on loads issued a full iter ago
        __syncthreads();
        calc_s9(sn, s9n);

        if (i < SD - 1) loadP(d + 2, P);   // prefetch: in flight across body

        #pragma unroll
        for (int v = 0; v < 2; v++) {
            const int j = 2 * hy + v;
            const float iv = img[(((size_t)b * DD + d) * HH + (h0 + j)) * WW + w];
            float summ = 0.f, sumbk = 0.f, cross = 0.f;
            #pragma unroll
            for (int k = 0; k < KK; k++) {
                const float m  = raw[((k * 3 + sc) * ROWS + (j + 1)) * COLS + (w + 1)];
                const float bk = s9p[k][v] + s9c[k][v] + s9n[k][v];
                summ  += m;
                sumbk += bk;
                cross += m * bk - m * m;
                smf[k] += m;
                sif[k] += m * iv;
                saf[k] += m * iv * iv;
            }
            j2f += summ * sumbk - summ * summ - cross;
        }

        #pragma unroll
        for (int k = 0; k < KK; k++) {
            s9p[k][0] = s9c[k][0]; s9p[k][1] = s9c[k][1];
            s9c[k][0] = s9n[k][0]; s9c[k][1] = s9n[k][1];
        }
    }

    // ---- block reduction of 13 scalars (f64) ----
    double q[13];
    #pragma unroll
    for (int k = 0; k < KK; k++) {
        q[k] = (double)smf[k]; q[4 + k] = (double)sif[k]; q[8 + k] = (double)saf[k];
    }
    q[12] = (double)j2f;

    #pragma unroll
    for (int qq = 0; qq < 13; qq++) {
        double v = q[qq];
        #pragma unroll
        for (int off = 32; off > 0; off >>= 1) v += __shfl_down(v, off, 64);
        q[qq] = v;
    }

    __syncthreads();                 // raw no longer needed
    double* red = (double*)raw;
    const int lane = tid & 63, wid = tid >> 6;
    if (lane == 0) {
        #pragma unroll
        for (int qq = 0; qq < 13; qq++) red[wid * 13 + qq] = q[qq];
    }
    __syncthreads();
    if (tid < 13) {
        const double s = red[tid] + red[13 + tid] + red[26 + tid] + red[39 + tid];
        int idx;
        if      (tid < 4)  idx = b * KK + tid;
        else if (tid < 8)  idx = 8  + b * KK + (tid - 4);
        else if (tid < 12) idx = 16 + b * KK + (tid - 8);
        else               idx = 24;
        unsafeAtomicAdd(&ws[idx], s);
    }
}

__global__ void rfcm_fin(const double* __restrict__ ws, float* __restrict__ out)
{
    if (threadIdx.x == 0 && blockIdx.x == 0) {
        double j1 = 0;
        #pragma unroll
        for (int i = 0; i < BB * KK; i++)
            j1 += ws[16 + i] - ws[8 + i] * ws[8 + i] / ws[i];
        const double invBN = 1.0 / ((double)BB * (double)DD * (double)HH * (double)WW);
        out[0] = (float)(j1 * invBN + 0.0008 * ws[24] * invBN);
    }
}

extern "C" void kernel_launch(void* const* d_in, const int* in_sizes, int n_in,
                              void* d_out, int out_size, void* d_ws, size_t ws_size,
                              hipStream_t stream) {
    const float* yp  = (const float*)d_in[0];   // y_pred [2,4,128,128,128]
    const float* img = (const float*)d_in[1];   // image  [2,1,128,128,128]
    float* out = (float*)d_out;
    double* ws = (double*)d_ws;

    hipMemsetAsync(d_ws, 0, 25 * sizeof(double), stream);

    dim3 grid(BB * NBD * NBH);   // 2048 blocks
    rfcm_main<<<grid, NT, 0, stream>>>(yp, img, ws);
    rfcm_fin<<<1, 64, 0, stream>>>(ws, out);
}

// Round 3
// 154.287 us; speedup vs baseline: 1.2916x; 1.1074x over previous
//
#include <hip/hip_runtime.h>

// RFCM loss, fused single pass + finalize. B=2, K=4, D=H=W=128. Scalar out.
//
// mean(J1) = (1/(B*N)) * sum_{b,k} [ A_bk - Sim_bk^2 / Sm_bk ]
//   Sm=sum mem, Sim=sum mem*img, A=sum mem*img^2, mem=y_pred^2
// mean(J2) = (1/(B*N)) * sum_n [ Sm*Sbk - Sm^2 - sum_k m*bk + sum_k m^2 ]
//   bk = box27(mem_k) incl center, zero pad.
//
// R3: no LDS staging, no barriers in hot loop. Thread owns 4 cols x 1 row;
// reads 3x6 window per cluster from global (L1/L2 resident), separable
// h3->w3 in registers, d-ring (hw9, m) in registers.

#define BB 2
#define KK 4
#define DD 128
#define HH 128
#define WW 128
#define PLANE (HH * WW)
#define SD 8
#define NBD (DD / SD)   // 16
#define HR 4            // rows per block
#define NBH (HH / HR)   // 32
#define NT 128          // 32 w-lanes x 4 rows

__global__ __launch_bounds__(NT) void rfcm_main(
    const float* __restrict__ yp, const float* __restrict__ img,
    double* __restrict__ ws)
{
    const int tid = threadIdx.x;
    const int wl  = tid & 31;       // w-lane: cols c0..c0+3
    const int hr  = tid >> 5;       // 0..3: own row
    const int c0  = wl << 2;

    int bid = blockIdx.x;
    const int ht  = bid % NBH; bid /= NBH;
    const int dsb = bid % NBD; bid /= NBD;
    const int b   = bid;
    const int h   = ht * HR + hr;
    const int d0  = dsb * SD;

    const bool okL = (wl > 0), okR = (wl < 31);
    const float msc = (h > 0)      ? 1.f : 0.f;   // zero row h-1 at boundary
    const float psc = (h < HH - 1) ? 1.f : 0.f;
    const int hm = (h > 0)      ? h - 1 : h;      // clamped (value zeroed via msc)
    const int hp = (h < HH - 1) ? h + 1 : h;

    const float* base = yp + (size_t)b * KK * DD * PLANE;
    const int offM = hm * WW + c0;
    const int off0 = h  * WW + c0;
    const int offP = hp * WW + c0;

    // computes hw9 (3x3 h,w box of mem) and center m for plane t, all k
    auto stepload = [&](int t, float4 (&s9)[KK], float4 (&mn)[KK]) {
        if ((unsigned)t < (unsigned)DD) {
            #pragma unroll
            for (int k = 0; k < KK; k++) {
                const float* pt = base + ((size_t)k * DD + t) * PLANE;
                const float4 a4 = *(const float4*)(pt + offM);
                const float  aL = okL ? pt[offM - 1] : 0.f;
                const float  aR = okR ? pt[offM + 4] : 0.f;
                const float4 b4 = *(const float4*)(pt + off0);
                const float  bL = okL ? pt[off0 - 1] : 0.f;
                const float  bR = okR ? pt[off0 + 4] : 0.f;
                const float4 c4 = *(const float4*)(pt + offP);
                const float  cL = okL ? pt[offP - 1] : 0.f;
                const float  cR = okR ? pt[offP + 4] : 0.f;

                float aa[6] = {aL*aL, a4.x*a4.x, a4.y*a4.y, a4.z*a4.z, a4.w*a4.w, aR*aR};
                float bb[6] = {bL*bL, b4.x*b4.x, b4.y*b4.y, b4.z*b4.z, b4.w*b4.w, bR*bR};
                float cc[6] = {cL*cL, c4.x*c4.x, c4.y*c4.y, c4.z*c4.z, c4.w*c4.w, cR*cR};

                mn[k] = make_float4(bb[1], bb[2], bb[3], bb[4]);

                float cs[6];
                #pragma unroll
                for (int j = 0; j < 6; j++)
                    cs[j] = fmaf(cc[j], psc, fmaf(aa[j], msc, bb[j]));

                s9[k].x = cs[0] + cs[1] + cs[2];
                s9[k].y = cs[1] + cs[2] + cs[3];
                s9[k].z = cs[2] + cs[3] + cs[4];
                s9[k].w = cs[3] + cs[4] + cs[5];
            }
        } else {
            #pragma unroll
            for (int k = 0; k < KK; k++) {
                s9[k] = make_float4(0.f, 0.f, 0.f, 0.f);
                mn[k] = make_float4(0.f, 0.f, 0.f, 0.f);
            }
        }
    };

    float4 s9p[KK], s9c[KK], s9n[KK], mc[KK], mn[KK];
    stepload(d0 - 1, s9p, mc);   // mc garbage here, overwritten next line
    stepload(d0,     s9c, mc);

    float smf[KK] = {0,0,0,0}, sif[KK] = {0,0,0,0}, saf[KK] = {0,0,0,0};
    float j2f = 0.f;

    const float* imgb = img + (size_t)b * DD * PLANE + off0;

    #pragma unroll 4
    for (int i = 0; i < SD; i++) {
        const int d = d0 + i;
        stepload(d + 1, s9n, mn);

        const float4 iv = *(const float4*)(imgb + (size_t)d * PLANE);
        const float4 iv2 = make_float4(iv.x*iv.x, iv.y*iv.y, iv.z*iv.z, iv.w*iv.w);

        float4 summ  = make_float4(0.f, 0.f, 0.f, 0.f);
        float4 sumbk = make_float4(0.f, 0.f, 0.f, 0.f);
        float4 cross = make_float4(0.f, 0.f, 0.f, 0.f);

        #pragma unroll
        for (int k = 0; k < KK; k++) {
            const float4 m = mc[k];
            float4 bk;
            bk.x = s9p[k].x + s9c[k].x + s9n[k].x;
            bk.y = s9p[k].y + s9c[k].y + s9n[k].y;
            bk.z = s9p[k].z + s9c[k].z + s9n[k].z;
            bk.w = s9p[k].w + s9c[k].w + s9n[k].w;

            summ.x += m.x; summ.y += m.y; summ.z += m.z; summ.w += m.w;
            sumbk.x += bk.x; sumbk.y += bk.y; sumbk.z += bk.z; sumbk.w += bk.w;
            cross.x = fmaf(m.x, bk.x - m.x, cross.x);
            cross.y = fmaf(m.y, bk.y - m.y, cross.y);
            cross.z = fmaf(m.z, bk.z - m.z, cross.z);
            cross.w = fmaf(m.w, bk.w - m.w, cross.w);

            smf[k] += (m.x + m.y) + (m.z + m.w);
            sif[k] = fmaf(m.x, iv.x,  fmaf(m.y, iv.y,  fmaf(m.z, iv.z,  fmaf(m.w, iv.w,  sif[k]))));
            saf[k] = fmaf(m.x, iv2.x, fmaf(m.y, iv2.y, fmaf(m.z, iv2.z, fmaf(m.w, iv2.w, saf[k]))));

            s9p[k] = s9c[k]; s9c[k] = s9n[k]; mc[k] = mn[k];
        }

        j2f += (summ.x * (sumbk.x - summ.x) - cross.x)
             + (summ.y * (sumbk.y - summ.y) - cross.y)
             + (summ.z * (sumbk.z - summ.z) - cross.z)
             + (summ.w * (sumbk.w - summ.w) - cross.w);
    }

    // ---- block reduction of 13 scalars ----
    double q[13];
    #pragma unroll
    for (int k = 0; k < KK; k++) {
        q[k] = (double)smf[k]; q[4 + k] = (double)sif[k]; q[8 + k] = (double)saf[k];
    }
    q[12] = (double)j2f;

    #pragma unroll
    for (int qq = 0; qq < 13; qq++) {
        double v = q[qq];
        #pragma unroll
        for (int off = 32; off > 0; off >>= 1) v += __shfl_down(v, off, 64);
        q[qq] = v;
    }

    __shared__ double red[2 * 13];
    const int lane = tid & 63, wid = tid >> 6;
    if (lane == 0) {
        #pragma unroll
        for (int qq = 0; qq < 13; qq++) red[wid * 13 + qq] = q[qq];
    }
    __syncthreads();
    if (tid < 13) {
        const double s = red[tid] + red[13 + tid];
        int idx;
        if      (tid < 4)  idx = b * KK + tid;              // Sm
        else if (tid < 8)  idx = 8  + b * KK + (tid - 4);   // Sim
        else if (tid < 12) idx = 16 + b * KK + (tid - 8);   // A
        else               idx = 24;                        // J2
        unsafeAtomicAdd(&ws[idx], s);
    }
}

__global__ void rfcm_fin(const double* __restrict__ ws, float* __restrict__ out)
{
    if (threadIdx.x == 0 && blockIdx.x == 0) {
        double j1 = 0;
        #pragma unroll
        for (int i = 0; i < BB * KK; i++)
            j1 += ws[16 + i] - ws[8 + i] * ws[8 + i] / ws[i];
        const double invBN = 1.0 / ((double)BB * (double)DD * (double)HH * (double)WW);
        out[0] = (float)(j1 * invBN + 0.0008 * ws[24] * invBN);
    }
}

extern "C" void kernel_launch(void* const* d_in, const int* in_sizes, int n_in,
                              void* d_out, int out_size, void* d_ws, size_t ws_size,
                              hipStream_t stream) {
    const float* yp  = (const float*)d_in[0];   // y_pred [2,4,128,128,128]
    const float* img = (const float*)d_in[1];   // image  [2,1,128,128,128]
    float* out = (float*)d_out;
    double* ws = (double*)d_ws;

    hipMemsetAsync(d_ws, 0, 25 * sizeof(double), stream);

    dim3 grid(BB * NBD * NBH);   // 1024 blocks
    rfcm_main<<<grid, NT, 0, stream>>>(yp, img, ws);
    rfcm_fin<<<1, 64, 0, stream>>>(ws, out);
}